// Round 7
// baseline (359.640 us; speedup 1.0000x reference)
//
#include <hip/hip_runtime.h>
#include <hip/hip_bf16.h>
#include <math.h>

#define B1 2048
#define B2 8192
#define NH 12
#define DH 64
#define DMODEL 768

typedef __attribute__((ext_vector_type(8))) short short8;
typedef __attribute__((ext_vector_type(4))) float floatx4;
typedef __attribute__((ext_vector_type(8))) unsigned short ushort8;
typedef __attribute__((ext_vector_type(4))) unsigned short ushort4v;

static __device__ __forceinline__ unsigned short f2bf(float f) {
  __bf16 b = (__bf16)f;
  return __builtin_bit_cast(unsigned short, b);
}
static __device__ __forceinline__ float bf2f(unsigned short u) {
  return __builtin_bit_cast(float, ((unsigned)u) << 16);
}

// async global->LDS, 16B per lane; LDS dest = wave-uniform base + lane*16
static __device__ __forceinline__ void gload16(const unsigned short* g,
                                               unsigned short* l) {
  __builtin_amdgcn_global_load_lds(
      (const __attribute__((address_space(1))) void*)g,
      (__attribute__((address_space(3))) void*)l, 16, 0, 0);
}

// ---------------------------------------------------------------------------
// Fused prep: ALL fp32 -> bf16 hi/lo splits + hi-only converts, one launch.
// block-role table: [0,1536) x1 | [1536,7680) x2 | [7680,8256) Wq |
// [8256,8832) Wk | [8832,9408) Wv(hi only) | [9408,9984) Wo(hi only)
// ---------------------------------------------------------------------------
__global__ __launch_bounds__(256) void prep_all(
    const float* __restrict__ x1, unsigned short* __restrict__ x1h,
    unsigned short* __restrict__ x1l, const float* __restrict__ x2,
    unsigned short* __restrict__ x2h, unsigned short* __restrict__ x2l,
    const float* __restrict__ Wq, unsigned short* __restrict__ Wqh,
    unsigned short* __restrict__ Wql, const float* __restrict__ Wk,
    unsigned short* __restrict__ Wkh, unsigned short* __restrict__ Wkl,
    const float* __restrict__ Wv, unsigned short* __restrict__ Wvh,
    const float* __restrict__ Wo, unsigned short* __restrict__ Woh) {
  const int bi = blockIdx.x;
  const float* src;
  unsigned short *hi, *lo = nullptr;
  int lb;
  if (bi < 1536) {
    src = x1; hi = x1h; lo = x1l; lb = bi;
  } else if (bi < 7680) {
    src = x2; hi = x2h; lo = x2l; lb = bi - 1536;
  } else if (bi < 8256) {
    src = Wq; hi = Wqh; lo = Wql; lb = bi - 7680;
  } else if (bi < 8832) {
    src = Wk; hi = Wkh; lo = Wkl; lb = bi - 8256;
  } else if (bi < 9408) {
    src = Wv; hi = Wvh; lb = bi - 8832;
  } else {
    src = Wo; hi = Woh; lb = bi - 9408;
  }
  const int i = (lb * 256 + threadIdx.x) * 4;
  const float4 v = *(const float4*)&src[i];
  ushort4v h = {f2bf(v.x), f2bf(v.y), f2bf(v.z), f2bf(v.w)};
  *(ushort4v*)&hi[i] = h;
  if (lo) {
    ushort4v l = {f2bf(v.x - bf2f(h[0])), f2bf(v.y - bf2f(h[1])),
                  f2bf(v.z - bf2f(h[2])), f2bf(v.w - bf2f(h[3]))};
    *(ushort4v*)&lo[i] = l;
  }
}

// ---------------------------------------------------------------------------
// Core bf16 MFMA GEMM tile: C[M,N] = A[M,K]*B[N,K]^T (both K-contiguous).
// 128x128 tile, BK=32, 4 waves (2x2), 64x64/wave, global_load_lds staging,
// XOR-swizzled granules. SPLIT: hi/lo 3-MFMA k-step (~fp32). L2N: per-64-col
// L2 norm epilogue.
// ---------------------------------------------------------------------------
template <bool SPLIT, bool L2N, bool F32OUT>
static __device__ __forceinline__ void gemm_tile(
    const unsigned short* __restrict__ Ahg, const unsigned short* __restrict__ Alg,
    const unsigned short* __restrict__ Bhg, const unsigned short* __restrict__ Blg,
    void* __restrict__ Cv, int M, int N, int K, int m0, int n0,
    unsigned short* sAh, unsigned short* sBh, unsigned short* sAl,
    unsigned short* sBl) {
  const int tid = threadIdx.x;
  const int wave = tid >> 6;
  const int lane = tid & 63;
  const int wm = wave >> 1;
  const int wn = wave & 1;
  const int n15 = lane & 15;
  const int quad = lane >> 4;
  const int srow = lane >> 2;
  const int cpl = (lane & 3) ^ (srow >> 2);

  floatx4 acc[4][4];
#pragma unroll
  for (int i = 0; i < 4; ++i)
#pragma unroll
    for (int j = 0; j < 4; ++j) acc[i][j] = (floatx4){0.f, 0.f, 0.f, 0.f};

  for (int k0 = 0; k0 < K; k0 += 32) {
    __syncthreads();
#pragma unroll
    for (int jj = 0; jj < 2; ++jj) {
      const int j = wave * 2 + jj;
      const int row = j * 16 + srow;
      const size_t goffA = (size_t)(m0 + row) * K + k0 + cpl * 8;
      const size_t goffB = (size_t)(n0 + row) * K + k0 + cpl * 8;
      gload16(Ahg + goffA, &sAh[j * 512]);
      gload16(Bhg + goffB, &sBh[j * 512]);
      if constexpr (SPLIT) {
        gload16(Alg + goffA, &sAl[j * 512]);
        gload16(Blg + goffB, &sBl[j * 512]);
      }
    }
    __syncthreads();

    short8 afh[4], afl[4];
#pragma unroll
    for (int mt = 0; mt < 4; ++mt) {
      const int row = wm * 64 + mt * 16 + n15;
      const int off = row * 32 + ((quad ^ (n15 >> 2)) << 3);
      afh[mt] = *(const short8*)&sAh[off];
      if constexpr (SPLIT) afl[mt] = *(const short8*)&sAl[off];
    }
#pragma unroll
    for (int nt = 0; nt < 4; ++nt) {
      const int row = wn * 64 + nt * 16 + n15;
      const int off = row * 32 + ((quad ^ (n15 >> 2)) << 3);
      const short8 bfh = *(const short8*)&sBh[off];
      if constexpr (SPLIT) {
        const short8 bfl = *(const short8*)&sBl[off];
#pragma unroll
        for (int mt = 0; mt < 4; ++mt) {
          acc[mt][nt] = __builtin_amdgcn_mfma_f32_16x16x32_bf16(afh[mt], bfh, acc[mt][nt], 0, 0, 0);
          acc[mt][nt] = __builtin_amdgcn_mfma_f32_16x16x32_bf16(afh[mt], bfl, acc[mt][nt], 0, 0, 0);
          acc[mt][nt] = __builtin_amdgcn_mfma_f32_16x16x32_bf16(afl[mt], bfh, acc[mt][nt], 0, 0, 0);
        }
      } else {
#pragma unroll
        for (int mt = 0; mt < 4; ++mt)
          acc[mt][nt] = __builtin_amdgcn_mfma_f32_16x16x32_bf16(afh[mt], bfh, acc[mt][nt], 0, 0, 0);
      }
    }
  }

#pragma unroll
  for (int mt = 0; mt < 4; ++mt) {
    float scalev[4] = {1.f, 1.f, 1.f, 1.f};
    if constexpr (L2N) {
#pragma unroll
      for (int rr = 0; rr < 4; ++rr) {
        float ss = 0.f;
#pragma unroll
        for (int nt = 0; nt < 4; ++nt) ss += acc[mt][nt][rr] * acc[mt][nt][rr];
        ss += __shfl_xor(ss, 1, 64);
        ss += __shfl_xor(ss, 2, 64);
        ss += __shfl_xor(ss, 4, 64);
        ss += __shfl_xor(ss, 8, 64);
        scalev[rr] = 1.0f / fmaxf(sqrtf(ss), 1e-12f);
      }
    }
#pragma unroll
    for (int nt = 0; nt < 4; ++nt) {
#pragma unroll
      for (int rr = 0; rr < 4; ++rr) {
        const int row = m0 + wm * 64 + mt * 16 + quad * 4 + rr;
        const int col = n0 + wn * 64 + nt * 16 + n15;
        const float v = acc[mt][nt][rr] * scalev[rr];
        if constexpr (F32OUT)
          ((float*)Cv)[(size_t)row * N + col] = v;
        else
          ((unsigned short*)Cv)[(size_t)row * N + col] = f2bf(v);
      }
    }
  }
}

// ---------------------------------------------------------------------------
// Fused q-proj + k-proj (both SPLIT + per-head L2N, bf16 out). 480 blocks.
// ---------------------------------------------------------------------------
__global__ __launch_bounds__(256) void qk_proj(
    const unsigned short* __restrict__ x1h, const unsigned short* __restrict__ x1l,
    const unsigned short* __restrict__ Wqh, const unsigned short* __restrict__ Wql,
    const unsigned short* __restrict__ x2h, const unsigned short* __restrict__ x2l,
    const unsigned short* __restrict__ Wkh, const unsigned short* __restrict__ Wkl,
    unsigned short* __restrict__ qbf, unsigned short* __restrict__ kbf) {
  __shared__ __align__(16) unsigned short sAh[4096], sBh[4096], sAl[4096], sBl[4096];
  const int bi = blockIdx.x;
  if (bi < 96) {
    gemm_tile<true, true, false>(x1h, x1l, Wqh, Wql, qbf, B1, DMODEL, DMODEL,
                                 (bi / 6) * 128, (bi % 6) * 128, sAh, sBh, sAl, sBl);
  } else {
    const int b = bi - 96;
    gemm_tile<true, true, false>(x2h, x2l, Wkh, Wkl, kbf, B2, DMODEL, DMODEL,
                                 (b / 6) * 128, (b % 6) * 128, sAh, sBh, sAl, sBl);
  }
}

// ---------------------------------------------------------------------------
// v-proj only (vt = Wv @ x2^T, plain bf16). 384 blocks.
// ---------------------------------------------------------------------------
__global__ __launch_bounds__(256) void v_proj(
    const unsigned short* __restrict__ Wvh, const unsigned short* __restrict__ x2h,
    unsigned short* __restrict__ vtbf) {
  __shared__ __align__(16) unsigned short sAh[4096], sBh[4096];
  const int bi = blockIdx.x;
  gemm_tile<false, false, false>(Wvh, nullptr, x2h, nullptr, vtbf, DMODEL, B2,
                                 DMODEL, (bi / 64) * 128, (bi % 64) * 128,
                                 sAh, sBh, nullptr, nullptr);
}

// ---------------------------------------------------------------------------
// MFMA bf16 attention — R6 structure, KSPLIT=3 for 4 blocks/CU occupancy:
//  - K staged in LDS with register prefetch; V read DIRECT from L2 (R6).
//  - P round-trip through wave-private LDS (Ps); slab plain stores (R6).
//  - KSPLIT=3 uneven: z0/z1 = 22 chunks (2816 keys), z2 = 20 chunks (2560).
//    Grid 1152 = 4.5 blocks/CU; LDS 33792 B allows 4 resident (was capped
//    at 3 by the 768-block grid).
//  - XCD swizzle for 1152 (bijective, 144/XCD; ~3.2 MB K+V per L2).
// ---------------------------------------------------------------------------
#define KC 128
#define KSPLIT 3
#define ZKEYS 2816  // keys per z-slab for z0/z1 (22 chunks); z2 = 2560 (20)
#define PSTR 68

__global__ __launch_bounds__(256, 4) void attn_mfma(
    const unsigned short* __restrict__ qb, const unsigned short* __restrict__ kb,
    const unsigned short* __restrict__ vt, float* __restrict__ aoacc,
    float* __restrict__ lacc, const int* __restrict__ invt_p) {
  __shared__ __align__(16) unsigned short smem[16896];  // 33792 B
  unsigned short* Kl = smem;            // [128 keys][64 dims], swizzled granules
  unsigned short* Psl = smem + 8192;    // 4 waves x 32 x PSTR

  // XCD swizzle: 1152 blocks, 144 consecutive swz per XCD (1152 = 8*144)
  const int bid = blockIdx.x;
  const int swz = (bid & 7) * 144 + (bid >> 3);
  const int zz = swz / 384;             // 0..2  (384 = 12h * 32 q-blocks)
  const int rem = swz - zz * 384;
  const int h = rem >> 5;
  const int q0 = (rem & 31) * 64;

  const float c2 = (float)invt_p[0] * 1.4426950408889634f;
  const int tid = threadIdx.x;
  const int wave = tid >> 6;
  const int lane = tid & 63;
  const int qsub = wave >> 1;
  const int ksub = wave & 1;
  const int n15 = lane & 15;
  const int quad = lane >> 4;
  const int kz0 = zz * ZKEYS;
  const int nch = (zz == 2) ? 20 : 22;

  unsigned short* Ps = &Psl[wave * 32 * PSTR];

  short8 qf[2][2];
#pragma unroll
  for (int qt = 0; qt < 2; ++qt)
#pragma unroll
    for (int ks = 0; ks < 2; ++ks) {
      const int qrow = q0 + qsub * 32 + qt * 16 + n15;
      qf[qt][ks] = *(const short8*)&qb[(size_t)qrow * DMODEL + h * DH + ks * 32 + quad * 8];
    }

  floatx4 oacc[2][4];
#pragma unroll
  for (int qt = 0; qt < 2; ++qt)
#pragma unroll
    for (int nt = 0; nt < 4; ++nt) oacc[qt][nt] = (floatx4){0.f, 0.f, 0.f, 0.f};
  float lsum[2] = {0.f, 0.f};

  const unsigned short* kbp = kb + (size_t)kz0 * DMODEL + h * DH;
  const unsigned short* vbp = vt + (size_t)(h * DH) * B2 + kz0;

  // K register prefetch (pre-swizzled global source, linear LDS store)
  ushort8 kr[4];
#pragma unroll
  for (int i = 0; i < 4; ++i) {
    const int s = i * 256 + tid;
    const int key = s >> 3, cpk = s & 7, chk = cpk ^ (key & 7);
    kr[i] = *(const ushort8*)&kbp[(size_t)key * DMODEL + chk * 8];
  }

  for (int c = 0; c < nch; ++c) {
    __syncthreads();
#pragma unroll
    for (int i = 0; i < 4; ++i) {
      const int s = i * 256 + tid;
      const int key = s >> 3, cpk = s & 7;
      *(ushort8*)&Kl[key * 64 + cpk * 8] = kr[i];
    }
    if (c + 1 < nch) {
      const unsigned short* kn = kbp + (size_t)(c + 1) * KC * DMODEL;
#pragma unroll
      for (int i = 0; i < 4; ++i) {
        const int s = i * 256 + tid;
        const int key = s >> 3, cpk = s & 7, chk = cpk ^ (key & 7);
        kr[i] = *(const ushort8*)&kn[(size_t)key * DMODEL + chk * 8];
      }
    }
    __syncthreads();

#pragma unroll
    for (int kt = 0; kt < 4; ++kt) {
      floatx4 s0 = {0.f, 0.f, 0.f, 0.f}, s1 = {0.f, 0.f, 0.f, 0.f};
#pragma unroll
      for (int ks = 0; ks < 2; ++ks) {
        const int key = ksub * 64 + kt * 16 + n15;
        const int cp = (ks * 4 + quad) ^ (n15 & 7);
        const short8 kf = *(const short8*)&Kl[key * 64 + cp * 8];
        s0 = __builtin_amdgcn_mfma_f32_16x16x32_bf16(kf, qf[0][ks], s0, 0, 0, 0);
        s1 = __builtin_amdgcn_mfma_f32_16x16x32_bf16(kf, qf[1][ks], s1, 0, 0, 0);
      }
      ushort4v p0, p1;
#pragma unroll
      for (int r = 0; r < 4; ++r) {
        const float e0 = exp2f(fmaf(s0[r], c2, -c2));
        const float e1 = exp2f(fmaf(s1[r], c2, -c2));
        lsum[0] += e0;
        lsum[1] += e1;
        p0[r] = f2bf(e0);
        p1[r] = f2bf(e1);
      }
      *(ushort4v*)&Ps[(0 * 16 + n15) * PSTR + kt * 16 + quad * 4] = p0;
      *(ushort4v*)&Ps[(1 * 16 + n15) * PSTR + kt * 16 + quad * 4] = p1;
    }

    const unsigned short* vc_ = vbp + c * KC;
#pragma unroll
    for (int ks = 0; ks < 2; ++ks) {
      short8 pa[2];
#pragma unroll
      for (int qt = 0; qt < 2; ++qt)
        pa[qt] = *(const short8*)&Ps[(qt * 16 + n15) * PSTR + ks * 32 + quad * 8];
#pragma unroll
      for (int nt = 0; nt < 4; ++nt) {
        const short8 vf = *(const short8*)&vc_[
            (size_t)(nt * 16 + n15) * B2 + (ksub * 8 + ks * 4 + quad) * 8];
        oacc[0][nt] = __builtin_amdgcn_mfma_f32_16x16x32_bf16(pa[0], vf, oacc[0][nt], 0, 0, 0);
        oacc[1][nt] = __builtin_amdgcn_mfma_f32_16x16x32_bf16(pa[1], vf, oacc[1][nt], 0, 0, 0);
      }
    }
  }

#pragma unroll
  for (int qt = 0; qt < 2; ++qt) {
    float v = lsum[qt];
    v += __shfl_xor(v, 16, 64);
    v += __shfl_xor(v, 32, 64);
    lsum[qt] = v;
  }

  float* aoz = aoacc + (size_t)zz * B1 * DMODEL;
  float* lz = lacc + (size_t)zz * B1 * NH;

  __syncthreads();
  float* Osc = (float*)smem;        // [64 q][64 d] f32 = 16384 B
  float* lsc = Osc + 4096;          // [64 q] f32 (total 16640 <= 33792)
  if (ksub == 1) {
#pragma unroll
    for (int qt = 0; qt < 2; ++qt)
#pragma unroll
      for (int nt = 0; nt < 4; ++nt)
#pragma unroll
        for (int r = 0; r < 4; ++r) {
          const int row = qsub * 32 + qt * 16 + quad * 4 + r;
          Osc[row * 64 + nt * 16 + n15] = oacc[qt][nt][r];
        }
    if (quad == 0) {
      lsc[qsub * 32 + n15] = lsum[0];
      lsc[qsub * 32 + 16 + n15] = lsum[1];
    }
  }
  __syncthreads();
  if (ksub == 0) {
#pragma unroll
    for (int qt = 0; qt < 2; ++qt)
#pragma unroll
      for (int nt = 0; nt < 4; ++nt)
#pragma unroll
        for (int r = 0; r < 4; ++r) {
          const int row = qsub * 32 + qt * 16 + quad * 4 + r;
          const float v = oacc[qt][nt][r] + Osc[row * 64 + nt * 16 + n15];
          aoz[(size_t)(q0 + row) * DMODEL + h * DH + nt * 16 + n15] = v;
        }
    if (quad == 0) {
      lz[(size_t)(q0 + qsub * 32 + n15) * NH + h] = lsum[0] + lsc[qsub * 32 + n15];
      lz[(size_t)(q0 + qsub * 32 + 16 + n15) * NH + h] =
          lsum[1] + lsc[qsub * 32 + 16 + n15];
    }
  }
}

// ---------------------------------------------------------------------------
// Wo projection with FUSED 3-slab-sum + ao-normalize in A-staging:
// A[row][col] = bf16( (ao0+ao1+ao2)[row][col] / (l0+l1+l2)[row][col>>6] ).
// B = Woh (gload16). C = f32 woout [B1, 768]. 96 blocks.
// ---------------------------------------------------------------------------
__global__ __launch_bounds__(256) void wo_proj(
    const float* __restrict__ aoacc, const float* __restrict__ lacc,
    const unsigned short* __restrict__ Woh, float* __restrict__ woout) {
  __shared__ __align__(16) unsigned short sAh[4096], sBh[4096];
  const int bi = blockIdx.x;
  const int m0 = (bi / 6) * 128;
  const int n0 = (bi % 6) * 128;
  const int tid = threadIdx.x;
  const int wave = tid >> 6;
  const int lane = tid & 63;
  const int wm = wave >> 1;
  const int wn = wave & 1;
  const int n15 = lane & 15;
  const int quad = lane >> 4;
  const int srow = lane >> 2;
  const int cpl = (lane & 3) ^ (srow >> 2);

  const float* ao1 = aoacc + (size_t)B1 * DMODEL;
  const float* ao2 = aoacc + (size_t)2 * B1 * DMODEL;
  const float* la1 = lacc + (size_t)B1 * NH;
  const float* la2 = lacc + (size_t)2 * B1 * NH;

  floatx4 acc[4][4];
#pragma unroll
  for (int i = 0; i < 4; ++i)
#pragma unroll
    for (int j = 0; j < 4; ++j) acc[i][j] = (floatx4){0.f, 0.f, 0.f, 0.f};

  for (int k0 = 0; k0 < DMODEL; k0 += 32) {
    __syncthreads();
#pragma unroll
    for (int jj = 0; jj < 2; ++jj) {
      const int j = wave * 2 + jj;
      const int row = j * 16 + srow;
      // A: load 8 f32 from each slab, sum, normalize, convert, ds_write 16B
      const size_t ga = (size_t)(m0 + row) * DMODEL + k0 + cpl * 8;
      const float4 a0 = *(const float4*)&aoacc[ga];
      const float4 a1 = *(const float4*)&aoacc[ga + 4];
      const float4 b0 = *(const float4*)&ao1[ga];
      const float4 b1 = *(const float4*)&ao1[ga + 4];
      const float4 c0 = *(const float4*)&ao2[ga];
      const float4 c1 = *(const float4*)&ao2[ga + 4];
      const int head = (k0 + cpl * 8) >> 6;
      const int li = (m0 + row) * NH + head;
      const float lsum = lacc[li] + la1[li] + la2[li];
      const float inv = 1.0f / lsum;
      ushort8 ah = {f2bf((a0.x + b0.x + c0.x) * inv), f2bf((a0.y + b0.y + c0.y) * inv),
                    f2bf((a0.z + b0.z + c0.z) * inv), f2bf((a0.w + b0.w + c0.w) * inv),
                    f2bf((a1.x + b1.x + c1.x) * inv), f2bf((a1.y + b1.y + c1.y) * inv),
                    f2bf((a1.z + b1.z + c1.z) * inv), f2bf((a1.w + b1.w + c1.w) * inv)};
      *(ushort8*)&sAh[j * 512 + lane * 8] = ah;
      // B: async staging
      gload16(Woh + (size_t)(n0 + row) * DMODEL + k0 + cpl * 8, &sBh[j * 512]);
    }
    __syncthreads();

    short8 afh[4];
#pragma unroll
    for (int mt = 0; mt < 4; ++mt) {
      const int row = wm * 64 + mt * 16 + n15;
      afh[mt] = *(const short8*)&sAh[row * 32 + ((quad ^ (n15 >> 2)) << 3)];
    }
#pragma unroll
    for (int nt = 0; nt < 4; ++nt) {
      const int row = wn * 64 + nt * 16 + n15;
      const short8 bfh = *(const short8*)&sBh[row * 32 + ((quad ^ (n15 >> 2)) << 3)];
#pragma unroll
      for (int mt = 0; mt < 4; ++mt)
        acc[mt][nt] = __builtin_amdgcn_mfma_f32_16x16x32_bf16(afh[mt], bfh, acc[mt][nt], 0, 0, 0);
    }
  }

#pragma unroll
  for (int mt = 0; mt < 4; ++mt)
#pragma unroll
    for (int nt = 0; nt < 4; ++nt)
#pragma unroll
      for (int rr = 0; rr < 4; ++rr) {
        const int row = m0 + wm * 64 + mt * 16 + quad * 4 + rr;
        const int col = n0 + wn * 64 + nt * 16 + n15;
        woout[(size_t)row * DMODEL + col] = acc[mt][nt][rr];
      }
}

// ---------------------------------------------------------------------------
__global__ __launch_bounds__(256) void l2norm_rows768_out(
    const float* __restrict__ x, float* __restrict__ out) {
  const int row = blockIdx.x;
  const float* xr = &x[(size_t)row * DMODEL];
  float ss = 0.0f;
  float vals[3];
#pragma unroll
  for (int i = 0; i < 3; ++i) {
    vals[i] = xr[threadIdx.x + i * 256];
    ss += vals[i] * vals[i];
  }
#pragma unroll
  for (int off = 32; off > 0; off >>= 1) ss += __shfl_xor(ss, off, 64);
  __shared__ float ws[4];
  if ((threadIdx.x & 63) == 0) ws[threadIdx.x >> 6] = ss;
  __syncthreads();
  const float tot = ws[0] + ws[1] + ws[2] + ws[3];
  const float sc = 1.0f / fmaxf(sqrtf(tot), 1e-12f);
  float* orow = &out[(size_t)row * DMODEL];
#pragma unroll
  for (int i = 0; i < 3; ++i) orow[threadIdx.x + i * 256] = vals[i] * sc;
}

// ---------------------------------------------------------------------------
extern "C" void kernel_launch(void* const* d_in, const int* in_sizes, int n_in,
                              void* d_out, int out_size, void* d_ws,
                              size_t ws_size, hipStream_t stream) {
  const float* x1 = (const float*)d_in[0];
  const float* x2 = (const float*)d_in[1];
  const float* Wq = (const float*)d_in[2];
  const float* Wk = (const float*)d_in[3];
  const float* Wv = (const float*)d_in[4];
  const float* Wo = (const float*)d_in[5];
  const int* invt = (const int*)d_in[6];
  float* outp = (float*)d_out;

  // workspace (bytes). Aliases are lifetime-safe under stream serialization:
  //  aoacc 3 slabs <- x1h/x1l/x2h (dead after v_proj)     [0,        18874368)
  //  vt_bf         <- x2l region (dead after qk_proj)     [18874368, 31457280)
  //  lacc 3 slabs  <- Wql region (dead after qk_proj)     [32636928, 32931840)
  //  woout         <- k_bf region (dead after attn)       [41680896, 47972352)
  char* ws = (char*)d_ws;
  unsigned short* x1h = (unsigned short*)(ws + 0);
  unsigned short* x1l = (unsigned short*)(ws + 3145728);
  unsigned short* x2h = (unsigned short*)(ws + 6291456);
  unsigned short* x2l = (unsigned short*)(ws + 18874368);
  unsigned short* Wqh = (unsigned short*)(ws + 31457280);
  unsigned short* Wql = (unsigned short*)(ws + 32636928);
  unsigned short* Wkh = (unsigned short*)(ws + 33816576);
  unsigned short* Wkl = (unsigned short*)(ws + 34996224);
  unsigned short* Wvh = (unsigned short*)(ws + 36175872);
  unsigned short* Woh = (unsigned short*)(ws + 37355520);
  unsigned short* q_bf = (unsigned short*)(ws + 38535168);
  unsigned short* k_bf = (unsigned short*)(ws + 41680896);   // end 54263808
  // aliases:
  float* aoacc = (float*)(ws + 0);                  // 3 slabs, 18874368 B
  float* lacc = (float*)(ws + 32636928);            // 3 slabs, 294912 B
  unsigned short* vt_bf = (unsigned short*)(ws + 18874368);
  float* woout = (float*)(ws + 41680896);

  // 1) all prep in one launch
  prep_all<<<9984, 256, 0, stream>>>(x1, x1h, x1l, x2, x2h, x2l, Wq, Wqh, Wql,
                                     Wk, Wkh, Wkl, Wv, Wvh, Wo, Woh);
  // 2) q-proj + k-proj fused (split precision + per-head l2norm)
  qk_proj<<<480, 256, 0, stream>>>(x1h, x1l, Wqh, Wql, x2h, x2l, Wkh, Wkl,
                                   q_bf, k_bf);
  // 3) v-proj
  v_proj<<<384, 256, 0, stream>>>(Wvh, x2h, vt_bf);
  // 4) attention (KSPLIT=3 -> 1152 blocks, 4 blocks/CU occupancy)
  attn_mfma<<<1152, 256, 0, stream>>>(q_bf, k_bf, vt_bf, aoacc, lacc, invt);
  // 5) Wo projection with fused 3-slab-sum + ao-normalize staging
  wo_proj<<<96, 256, 0, stream>>>(aoacc, lacc, Woh, woout);
  // 6) final row l2norm
  l2norm_rows768_out<<<B1, 256, 0, stream>>>(woout, outp);
}

// Round 8
// 318.155 us; speedup vs baseline: 1.1304x; 1.1304x over previous
//
#include <hip/hip_runtime.h>
#include <hip/hip_bf16.h>
#include <math.h>

#define B1 2048
#define B2 8192
#define NH 12
#define DH 64
#define DMODEL 768

typedef __attribute__((ext_vector_type(8))) short short8;
typedef __attribute__((ext_vector_type(4))) float floatx4;
typedef __attribute__((ext_vector_type(8))) unsigned short ushort8;
typedef __attribute__((ext_vector_type(4))) unsigned short ushort4v;

static __device__ __forceinline__ unsigned short f2bf(float f) {
  __bf16 b = (__bf16)f;
  return __builtin_bit_cast(unsigned short, b);
}
static __device__ __forceinline__ float bf2f(unsigned short u) {
  return __builtin_bit_cast(float, ((unsigned)u) << 16);
}

// async global->LDS, 16B per lane; LDS dest = wave-uniform base + lane*16
static __device__ __forceinline__ void gload16(const unsigned short* g,
                                               unsigned short* l) {
  __builtin_amdgcn_global_load_lds(
      (const __attribute__((address_space(1))) void*)g,
      (__attribute__((address_space(3))) void*)l, 16, 0, 0);
}

// ---------------------------------------------------------------------------
// Fused prep: ALL fp32 -> bf16 hi/lo splits + hi-only converts, one launch.
// block-role table: [0,1536) x1 | [1536,7680) x2 | [7680,8256) Wq |
// [8256,8832) Wk | [8832,9408) Wv(hi only) | [9408,9984) Wo(hi only)
// ---------------------------------------------------------------------------
__global__ __launch_bounds__(256) void prep_all(
    const float* __restrict__ x1, unsigned short* __restrict__ x1h,
    unsigned short* __restrict__ x1l, const float* __restrict__ x2,
    unsigned short* __restrict__ x2h, unsigned short* __restrict__ x2l,
    const float* __restrict__ Wq, unsigned short* __restrict__ Wqh,
    unsigned short* __restrict__ Wql, const float* __restrict__ Wk,
    unsigned short* __restrict__ Wkh, unsigned short* __restrict__ Wkl,
    const float* __restrict__ Wv, unsigned short* __restrict__ Wvh,
    const float* __restrict__ Wo, unsigned short* __restrict__ Woh) {
  const int bi = blockIdx.x;
  const float* src;
  unsigned short *hi, *lo = nullptr;
  int lb;
  if (bi < 1536) {
    src = x1; hi = x1h; lo = x1l; lb = bi;
  } else if (bi < 7680) {
    src = x2; hi = x2h; lo = x2l; lb = bi - 1536;
  } else if (bi < 8256) {
    src = Wq; hi = Wqh; lo = Wql; lb = bi - 7680;
  } else if (bi < 8832) {
    src = Wk; hi = Wkh; lo = Wkl; lb = bi - 8256;
  } else if (bi < 9408) {
    src = Wv; hi = Wvh; lb = bi - 8832;
  } else {
    src = Wo; hi = Woh; lb = bi - 9408;
  }
  const int i = (lb * 256 + threadIdx.x) * 4;
  const float4 v = *(const float4*)&src[i];
  ushort4v h = {f2bf(v.x), f2bf(v.y), f2bf(v.z), f2bf(v.w)};
  *(ushort4v*)&hi[i] = h;
  if (lo) {
    ushort4v l = {f2bf(v.x - bf2f(h[0])), f2bf(v.y - bf2f(h[1])),
                  f2bf(v.z - bf2f(h[2])), f2bf(v.w - bf2f(h[3]))};
    *(ushort4v*)&lo[i] = l;
  }
}

// ---------------------------------------------------------------------------
// Core bf16 MFMA GEMM tile: C[M,N] = A[M,K]*B[N,K]^T (both K-contiguous).
// 128x128 tile, BK=32, 4 waves (2x2), 64x64/wave, global_load_lds staging,
// XOR-swizzled granules. SPLIT: hi/lo 3-MFMA k-step (~fp32). L2N: per-64-col
// L2 norm epilogue.
// ---------------------------------------------------------------------------
template <bool SPLIT, bool L2N, bool F32OUT>
static __device__ __forceinline__ void gemm_tile(
    const unsigned short* __restrict__ Ahg, const unsigned short* __restrict__ Alg,
    const unsigned short* __restrict__ Bhg, const unsigned short* __restrict__ Blg,
    void* __restrict__ Cv, int M, int N, int K, int m0, int n0,
    unsigned short* sAh, unsigned short* sBh, unsigned short* sAl,
    unsigned short* sBl) {
  const int tid = threadIdx.x;
  const int wave = tid >> 6;
  const int lane = tid & 63;
  const int wm = wave >> 1;
  const int wn = wave & 1;
  const int n15 = lane & 15;
  const int quad = lane >> 4;
  const int srow = lane >> 2;
  const int cpl = (lane & 3) ^ (srow >> 2);

  floatx4 acc[4][4];
#pragma unroll
  for (int i = 0; i < 4; ++i)
#pragma unroll
    for (int j = 0; j < 4; ++j) acc[i][j] = (floatx4){0.f, 0.f, 0.f, 0.f};

  for (int k0 = 0; k0 < K; k0 += 32) {
    __syncthreads();
#pragma unroll
    for (int jj = 0; jj < 2; ++jj) {
      const int j = wave * 2 + jj;
      const int row = j * 16 + srow;
      const size_t goffA = (size_t)(m0 + row) * K + k0 + cpl * 8;
      const size_t goffB = (size_t)(n0 + row) * K + k0 + cpl * 8;
      gload16(Ahg + goffA, &sAh[j * 512]);
      gload16(Bhg + goffB, &sBh[j * 512]);
      if constexpr (SPLIT) {
        gload16(Alg + goffA, &sAl[j * 512]);
        gload16(Blg + goffB, &sBl[j * 512]);
      }
    }
    __syncthreads();

    short8 afh[4], afl[4];
#pragma unroll
    for (int mt = 0; mt < 4; ++mt) {
      const int row = wm * 64 + mt * 16 + n15;
      const int off = row * 32 + ((quad ^ (n15 >> 2)) << 3);
      afh[mt] = *(const short8*)&sAh[off];
      if constexpr (SPLIT) afl[mt] = *(const short8*)&sAl[off];
    }
#pragma unroll
    for (int nt = 0; nt < 4; ++nt) {
      const int row = wn * 64 + nt * 16 + n15;
      const int off = row * 32 + ((quad ^ (n15 >> 2)) << 3);
      const short8 bfh = *(const short8*)&sBh[off];
      if constexpr (SPLIT) {
        const short8 bfl = *(const short8*)&sBl[off];
#pragma unroll
        for (int mt = 0; mt < 4; ++mt) {
          acc[mt][nt] = __builtin_amdgcn_mfma_f32_16x16x32_bf16(afh[mt], bfh, acc[mt][nt], 0, 0, 0);
          acc[mt][nt] = __builtin_amdgcn_mfma_f32_16x16x32_bf16(afh[mt], bfl, acc[mt][nt], 0, 0, 0);
          acc[mt][nt] = __builtin_amdgcn_mfma_f32_16x16x32_bf16(afl[mt], bfh, acc[mt][nt], 0, 0, 0);
        }
      } else {
#pragma unroll
        for (int mt = 0; mt < 4; ++mt)
          acc[mt][nt] = __builtin_amdgcn_mfma_f32_16x16x32_bf16(afh[mt], bfh, acc[mt][nt], 0, 0, 0);
      }
    }
  }

#pragma unroll
  for (int mt = 0; mt < 4; ++mt) {
    float scalev[4] = {1.f, 1.f, 1.f, 1.f};
    if constexpr (L2N) {
#pragma unroll
      for (int rr = 0; rr < 4; ++rr) {
        float ss = 0.f;
#pragma unroll
        for (int nt = 0; nt < 4; ++nt) ss += acc[mt][nt][rr] * acc[mt][nt][rr];
        ss += __shfl_xor(ss, 1, 64);
        ss += __shfl_xor(ss, 2, 64);
        ss += __shfl_xor(ss, 4, 64);
        ss += __shfl_xor(ss, 8, 64);
        scalev[rr] = 1.0f / fmaxf(sqrtf(ss), 1e-12f);
      }
    }
#pragma unroll
    for (int nt = 0; nt < 4; ++nt) {
#pragma unroll
      for (int rr = 0; rr < 4; ++rr) {
        const int row = m0 + wm * 64 + mt * 16 + quad * 4 + rr;
        const int col = n0 + wn * 64 + nt * 16 + n15;
        const float v = acc[mt][nt][rr] * scalev[rr];
        if constexpr (F32OUT)
          ((float*)Cv)[(size_t)row * N + col] = v;
        else
          ((unsigned short*)Cv)[(size_t)row * N + col] = f2bf(v);
      }
    }
  }
}

// ---------------------------------------------------------------------------
// Fused q-proj + k-proj (both SPLIT + per-head L2N, bf16 out). 480 blocks.
// ---------------------------------------------------------------------------
__global__ __launch_bounds__(256) void qk_proj(
    const unsigned short* __restrict__ x1h, const unsigned short* __restrict__ x1l,
    const unsigned short* __restrict__ Wqh, const unsigned short* __restrict__ Wql,
    const unsigned short* __restrict__ x2h, const unsigned short* __restrict__ x2l,
    const unsigned short* __restrict__ Wkh, const unsigned short* __restrict__ Wkl,
    unsigned short* __restrict__ qbf, unsigned short* __restrict__ kbf) {
  __shared__ __align__(16) unsigned short sAh[4096], sBh[4096], sAl[4096], sBl[4096];
  const int bi = blockIdx.x;
  if (bi < 96) {
    gemm_tile<true, true, false>(x1h, x1l, Wqh, Wql, qbf, B1, DMODEL, DMODEL,
                                 (bi / 6) * 128, (bi % 6) * 128, sAh, sBh, sAl, sBl);
  } else {
    const int b = bi - 96;
    gemm_tile<true, true, false>(x2h, x2l, Wkh, Wkl, kbf, B2, DMODEL, DMODEL,
                                 (b / 6) * 128, (b % 6) * 128, sAh, sBh, sAl, sBl);
  }
}

// ---------------------------------------------------------------------------
// v-proj only (vt = Wv @ x2^T, plain bf16). 384 blocks.
// ---------------------------------------------------------------------------
__global__ __launch_bounds__(256) void v_proj(
    const unsigned short* __restrict__ Wvh, const unsigned short* __restrict__ x2h,
    unsigned short* __restrict__ vtbf) {
  __shared__ __align__(16) unsigned short sAh[4096], sBh[4096];
  const int bi = blockIdx.x;
  gemm_tile<false, false, false>(Wvh, nullptr, x2h, nullptr, vtbf, DMODEL, B2,
                                 DMODEL, (bi / 64) * 128, (bi % 64) * 128,
                                 sAh, sBh, nullptr, nullptr);
}

// ---------------------------------------------------------------------------
// MFMA bf16 attention — R6 math, software-pipelined chunk loop:
//  - K LDS DOUBLE-BUFFERED -> ONE barrier per chunk (was 2). Invariant:
//    chunk c reads buf c&1; stages c+1 into the other buf (safe: end-of-
//    chunk-(c-1) barrier guaranteed its readers finished); the single
//    end-of-chunk barrier publishes the staged buffer.
//  - K global prefetch 2 chunks deep (kr regs).
//  - V loads hoisted to chunk START into regs (vr), consumed by PV of the
//    SAME chunk: QK+softmax (~400cyc) covers L2 latency, and vr is fully
//    consumed before the barrier so the vmcnt drain doesn't wait on it.
//  - Everything else identical to R6 (verified): Ps wave-private LDS,
//    slab plain stores, XCD swizzle (768 = 8*96), KSPLIT=2.
// ---------------------------------------------------------------------------
#define KC 128
#define KSPLIT 2
#define NCH (B2 / KSPLIT / KC)  // 32
#define PSTR 68

__global__ __launch_bounds__(256, 3) void attn_mfma(
    const unsigned short* __restrict__ qb, const unsigned short* __restrict__ kb,
    const unsigned short* __restrict__ vt, float* __restrict__ aoacc,
    float* __restrict__ lacc, const int* __restrict__ invt_p) {
  __shared__ __align__(16) unsigned short smem[25088];  // 50176 B
  // Kl dbuf: [2][128 keys][64 dims] at smem+0 / smem+8192 (shorts)
  unsigned short* Psl = smem + 16384;   // 4 waves x 32 x PSTR

  const int bid = blockIdx.x;                     // 0..767
  const int swz = (bid & 7) * 96 + (bid >> 3);    // bijective (768 % 8 == 0)
  const int zz = swz / 384;
  const int rem = swz - zz * 384;
  const int h = rem >> 5;
  const int q0 = (rem & 31) * 64;

  const float c2 = (float)invt_p[0] * 1.4426950408889634f;
  const int tid = threadIdx.x;
  const int wave = tid >> 6;
  const int lane = tid & 63;
  const int qsub = wave >> 1;
  const int ksub = wave & 1;
  const int n15 = lane & 15;
  const int quad = lane >> 4;
  const int kz0 = zz * (B2 / KSPLIT);

  unsigned short* Ps = &Psl[wave * 32 * PSTR];

  short8 qf[2][2];
#pragma unroll
  for (int qt = 0; qt < 2; ++qt)
#pragma unroll
    for (int ks = 0; ks < 2; ++ks) {
      const int qrow = q0 + qsub * 32 + qt * 16 + n15;
      qf[qt][ks] = *(const short8*)&qb[(size_t)qrow * DMODEL + h * DH + ks * 32 + quad * 8];
    }

  floatx4 oacc[2][4];
#pragma unroll
  for (int qt = 0; qt < 2; ++qt)
#pragma unroll
    for (int nt = 0; nt < 4; ++nt) oacc[qt][nt] = (floatx4){0.f, 0.f, 0.f, 0.f};
  float lsum[2] = {0.f, 0.f};

  const unsigned short* kbp = kb + (size_t)kz0 * DMODEL + h * DH;
  const unsigned short* vbp = vt + (size_t)(h * DH) * B2 + kz0;

  // prologue: load K chunk0 -> stage buf0 -> load K chunk1 -> barrier
  ushort8 kr[4];
#pragma unroll
  for (int i = 0; i < 4; ++i) {
    const int s = i * 256 + tid;
    const int key = s >> 3, cpk = s & 7, chk = cpk ^ (key & 7);
    kr[i] = *(const ushort8*)&kbp[(size_t)key * DMODEL + chk * 8];
  }
#pragma unroll
  for (int i = 0; i < 4; ++i) {
    const int s = i * 256 + tid;
    const int key = s >> 3, cpk = s & 7;
    *(ushort8*)&smem[key * 64 + cpk * 8] = kr[i];
  }
#pragma unroll
  for (int i = 0; i < 4; ++i) {
    const int s = i * 256 + tid;
    const int key = s >> 3, cpk = s & 7, chk = cpk ^ (key & 7);
    kr[i] = *(const ushort8*)&kbp[(size_t)(KC + key) * DMODEL + chk * 8];
  }
  __syncthreads();

  for (int c = 0; c < NCH; ++c) {
    unsigned short* Kb = &smem[(c & 1) * 8192];
    unsigned short* Kn = &smem[((c + 1) & 1) * 8192];
    const unsigned short* vc_ = vbp + c * KC;

    // early V issue for THIS chunk (consumed in PV below)
    ushort8 vr[8];
#pragma unroll
    for (int ks = 0; ks < 2; ++ks)
#pragma unroll
      for (int nt = 0; nt < 4; ++nt)
        vr[ks * 4 + nt] = *(const ushort8*)&vc_[
            (size_t)(nt * 16 + n15) * B2 + (ksub * 8 + ks * 4 + quad) * 8];

    // stage chunk c+1 into the other buffer; load chunk c+2
    if (c + 1 < NCH) {
#pragma unroll
      for (int i = 0; i < 4; ++i) {
        const int s = i * 256 + tid;
        const int key = s >> 3, cpk = s & 7;
        *(ushort8*)&Kn[key * 64 + cpk * 8] = kr[i];
      }
      if (c + 2 < NCH) {
        const unsigned short* k2 = kbp + (size_t)(c + 2) * KC * DMODEL;
#pragma unroll
        for (int i = 0; i < 4; ++i) {
          const int s = i * 256 + tid;
          const int key = s >> 3, cpk = s & 7, chk = cpk ^ (key & 7);
          kr[i] = *(const ushort8*)&k2[(size_t)key * DMODEL + chk * 8];
        }
      }
    }

    // ---- QK^T from Kb ----
#pragma unroll
    for (int kt = 0; kt < 4; ++kt) {
      floatx4 s0 = {0.f, 0.f, 0.f, 0.f}, s1 = {0.f, 0.f, 0.f, 0.f};
#pragma unroll
      for (int ks = 0; ks < 2; ++ks) {
        const int key = ksub * 64 + kt * 16 + n15;
        const int cp = (ks * 4 + quad) ^ (n15 & 7);
        const short8 kf = *(const short8*)&Kb[key * 64 + cp * 8];
        s0 = __builtin_amdgcn_mfma_f32_16x16x32_bf16(kf, qf[0][ks], s0, 0, 0, 0);
        s1 = __builtin_amdgcn_mfma_f32_16x16x32_bf16(kf, qf[1][ks], s1, 0, 0, 0);
      }
      ushort4v p0, p1;
#pragma unroll
      for (int r = 0; r < 4; ++r) {
        const float e0 = exp2f(fmaf(s0[r], c2, -c2));
        const float e1 = exp2f(fmaf(s1[r], c2, -c2));
        lsum[0] += e0;
        lsum[1] += e1;
        p0[r] = f2bf(e0);
        p1[r] = f2bf(e1);
      }
      *(ushort4v*)&Ps[(0 * 16 + n15) * PSTR + kt * 16 + quad * 4] = p0;
      *(ushort4v*)&Ps[(1 * 16 + n15) * PSTR + kt * 16 + quad * 4] = p1;
    }

    // ---- PV using prefetched vr ----
#pragma unroll
    for (int ks = 0; ks < 2; ++ks) {
      short8 pa[2];
#pragma unroll
      for (int qt = 0; qt < 2; ++qt)
        pa[qt] = *(const short8*)&Ps[(qt * 16 + n15) * PSTR + ks * 32 + quad * 8];
#pragma unroll
      for (int nt = 0; nt < 4; ++nt) {
        const short8 vf = __builtin_bit_cast(short8, vr[ks * 4 + nt]);
        oacc[0][nt] = __builtin_amdgcn_mfma_f32_16x16x32_bf16(pa[0], vf, oacc[0][nt], 0, 0, 0);
        oacc[1][nt] = __builtin_amdgcn_mfma_f32_16x16x32_bf16(pa[1], vf, oacc[1][nt], 0, 0, 0);
      }
    }

    __syncthreads();  // publish Kn; prior Kb readers done before next overwrite
  }

#pragma unroll
  for (int qt = 0; qt < 2; ++qt) {
    float v = lsum[qt];
    v += __shfl_xor(v, 16, 64);
    v += __shfl_xor(v, 32, 64);
    lsum[qt] = v;
  }

  float* aoz = aoacc + (size_t)zz * B1 * DMODEL;
  float* lz = lacc + (size_t)zz * B1 * NH;

  __syncthreads();
  float* Osc = (float*)smem;        // [64 q][64 d] f32 = 16384 B
  float* lsc = Osc + 4096;          // [64 q] f32 (total 16640 <= 50176)
  if (ksub == 1) {
#pragma unroll
    for (int qt = 0; qt < 2; ++qt)
#pragma unroll
      for (int nt = 0; nt < 4; ++nt)
#pragma unroll
        for (int r = 0; r < 4; ++r) {
          const int row = qsub * 32 + qt * 16 + quad * 4 + r;
          Osc[row * 64 + nt * 16 + n15] = oacc[qt][nt][r];
        }
    if (quad == 0) {
      lsc[qsub * 32 + n15] = lsum[0];
      lsc[qsub * 32 + 16 + n15] = lsum[1];
    }
  }
  __syncthreads();
  if (ksub == 0) {
#pragma unroll
    for (int qt = 0; qt < 2; ++qt)
#pragma unroll
      for (int nt = 0; nt < 4; ++nt)
#pragma unroll
        for (int r = 0; r < 4; ++r) {
          const int row = qsub * 32 + qt * 16 + quad * 4 + r;
          const float v = oacc[qt][nt][r] + Osc[row * 64 + nt * 16 + n15];
          aoz[(size_t)(q0 + row) * DMODEL + h * DH + nt * 16 + n15] = v;
        }
    if (quad == 0) {
      lz[(size_t)(q0 + qsub * 32 + n15) * NH + h] = lsum[0] + lsc[qsub * 32 + n15];
      lz[(size_t)(q0 + qsub * 32 + 16 + n15) * NH + h] =
          lsum[1] + lsc[qsub * 32 + 16 + n15];
    }
  }
}

// ---------------------------------------------------------------------------
// Wo projection with FUSED slab-sum + ao-normalize in A-staging:
// A[row][col] = bf16( (ao0+ao1)[row][col] / (l0+l1)[row][col>>6] ).
// B = Woh (gload16). C = f32 woout [B1, 768]. 96 blocks.
// ---------------------------------------------------------------------------
__global__ __launch_bounds__(256) void wo_proj(
    const float* __restrict__ aoacc, const float* __restrict__ lacc,
    const unsigned short* __restrict__ Woh, float* __restrict__ woout) {
  __shared__ __align__(16) unsigned short sAh[4096], sBh[4096];
  const int bi = blockIdx.x;
  const int m0 = (bi / 6) * 128;
  const int n0 = (bi % 6) * 128;
  const int tid = threadIdx.x;
  const int wave = tid >> 6;
  const int lane = tid & 63;
  const int wm = wave >> 1;
  const int wn = wave & 1;
  const int n15 = lane & 15;
  const int quad = lane >> 4;
  const int srow = lane >> 2;
  const int cpl = (lane & 3) ^ (srow >> 2);

  const float* ao1 = aoacc + (size_t)B1 * DMODEL;
  const float* la1 = lacc + (size_t)B1 * NH;

  floatx4 acc[4][4];
#pragma unroll
  for (int i = 0; i < 4; ++i)
#pragma unroll
    for (int j = 0; j < 4; ++j) acc[i][j] = (floatx4){0.f, 0.f, 0.f, 0.f};

  for (int k0 = 0; k0 < DMODEL; k0 += 32) {
    __syncthreads();
#pragma unroll
    for (int jj = 0; jj < 2; ++jj) {
      const int j = wave * 2 + jj;
      const int row = j * 16 + srow;
      // A: load 8 f32 from each slab, sum, normalize, convert, ds_write 16B
      const size_t ga = (size_t)(m0 + row) * DMODEL + k0 + cpl * 8;
      const float4 a0 = *(const float4*)&aoacc[ga];
      const float4 a1 = *(const float4*)&aoacc[ga + 4];
      const float4 b0 = *(const float4*)&ao1[ga];
      const float4 b1 = *(const float4*)&ao1[ga + 4];
      const int head = (k0 + cpl * 8) >> 6;
      const float lsum = lacc[(m0 + row) * NH + head] + la1[(m0 + row) * NH + head];
      const float inv = 1.0f / lsum;
      ushort8 ah = {f2bf((a0.x + b0.x) * inv), f2bf((a0.y + b0.y) * inv),
                    f2bf((a0.z + b0.z) * inv), f2bf((a0.w + b0.w) * inv),
                    f2bf((a1.x + b1.x) * inv), f2bf((a1.y + b1.y) * inv),
                    f2bf((a1.z + b1.z) * inv), f2bf((a1.w + b1.w) * inv)};
      *(ushort8*)&sAh[j * 512 + lane * 8] = ah;
      // B: async staging
      gload16(Woh + (size_t)(n0 + row) * DMODEL + k0 + cpl * 8, &sBh[j * 512]);
    }
    __syncthreads();

    short8 afh[4];
#pragma unroll
    for (int mt = 0; mt < 4; ++mt) {
      const int row = wm * 64 + mt * 16 + n15;
      afh[mt] = *(const short8*)&sAh[row * 32 + ((quad ^ (n15 >> 2)) << 3)];
    }
#pragma unroll
    for (int nt = 0; nt < 4; ++nt) {
      const int row = wn * 64 + nt * 16 + n15;
      const short8 bfh = *(const short8*)&sBh[row * 32 + ((quad ^ (n15 >> 2)) << 3)];
#pragma unroll
      for (int mt = 0; mt < 4; ++mt)
        acc[mt][nt] = __builtin_amdgcn_mfma_f32_16x16x32_bf16(afh[mt], bfh, acc[mt][nt], 0, 0, 0);
    }
  }

#pragma unroll
  for (int mt = 0; mt < 4; ++mt)
#pragma unroll
    for (int nt = 0; nt < 4; ++nt)
#pragma unroll
      for (int rr = 0; rr < 4; ++rr) {
        const int row = m0 + wm * 64 + mt * 16 + quad * 4 + rr;
        const int col = n0 + wn * 64 + nt * 16 + n15;
        woout[(size_t)row * DMODEL + col] = acc[mt][nt][rr];
      }
}

// ---------------------------------------------------------------------------
__global__ __launch_bounds__(256) void l2norm_rows768_out(
    const float* __restrict__ x, float* __restrict__ out) {
  const int row = blockIdx.x;
  const float* xr = &x[(size_t)row * DMODEL];
  float ss = 0.0f;
  float vals[3];
#pragma unroll
  for (int i = 0; i < 3; ++i) {
    vals[i] = xr[threadIdx.x + i * 256];
    ss += vals[i] * vals[i];
  }
#pragma unroll
  for (int off = 32; off > 0; off >>= 1) ss += __shfl_xor(ss, off, 64);
  __shared__ float ws[4];
  if ((threadIdx.x & 63) == 0) ws[threadIdx.x >> 6] = ss;
  __syncthreads();
  const float tot = ws[0] + ws[1] + ws[2] + ws[3];
  const float sc = 1.0f / fmaxf(sqrtf(tot), 1e-12f);
  float* orow = &out[(size_t)row * DMODEL];
#pragma unroll
  for (int i = 0; i < 3; ++i) orow[threadIdx.x + i * 256] = vals[i] * sc;
}

// ---------------------------------------------------------------------------
extern "C" void kernel_launch(void* const* d_in, const int* in_sizes, int n_in,
                              void* d_out, int out_size, void* d_ws,
                              size_t ws_size, hipStream_t stream) {
  const float* x1 = (const float*)d_in[0];
  const float* x2 = (const float*)d_in[1];
  const float* Wq = (const float*)d_in[2];
  const float* Wk = (const float*)d_in[3];
  const float* Wv = (const float*)d_in[4];
  const float* Wo = (const float*)d_in[5];
  const int* invt = (const int*)d_in[6];
  float* outp = (float*)d_out;

  // workspace (bytes). Aliases are lifetime-safe under stream serialization:
  //  aoacc slab0 <- x1h/x1l region (dead after qk_proj)     [0,        6291456)
  //  aoacc slab1 <- x2h first half (dead after v_proj)      [6291456, 12582912)
  //  woout       <- x2h second half (dead after v_proj)     [12582912,18874368)
  //  vt_bf       <- x2l region (dead after qk_proj)         [18874368,31457280)
  //  lacc slabs  <- Wql region (dead after qk_proj)         [32636928,32833536)
  char* ws = (char*)d_ws;
  unsigned short* x1h = (unsigned short*)(ws + 0);
  unsigned short* x1l = (unsigned short*)(ws + 3145728);
  unsigned short* x2h = (unsigned short*)(ws + 6291456);
  unsigned short* x2l = (unsigned short*)(ws + 18874368);
  unsigned short* Wqh = (unsigned short*)(ws + 31457280);
  unsigned short* Wql = (unsigned short*)(ws + 32636928);
  unsigned short* Wkh = (unsigned short*)(ws + 33816576);
  unsigned short* Wkl = (unsigned short*)(ws + 34996224);
  unsigned short* Wvh = (unsigned short*)(ws + 36175872);
  unsigned short* Woh = (unsigned short*)(ws + 37355520);
  unsigned short* q_bf = (unsigned short*)(ws + 38535168);
  unsigned short* k_bf = (unsigned short*)(ws + 41680896);   // end 54263808
  // aliases:
  float* aoacc = (float*)(ws + 0);                  // 2 slabs, 12582912 B
  float* lacc = (float*)(ws + 32636928);            // 2 slabs, 196608 B
  unsigned short* vt_bf = (unsigned short*)(ws + 18874368);
  float* woout = (float*)(ws + 12582912);

  // 1) all prep in one launch
  prep_all<<<9984, 256, 0, stream>>>(x1, x1h, x1l, x2, x2h, x2l, Wq, Wqh, Wql,
                                     Wk, Wkh, Wkl, Wv, Wvh, Wo, Woh);
  // 2) q-proj + k-proj fused (split precision + per-head l2norm)
  qk_proj<<<480, 256, 0, stream>>>(x1h, x1l, Wqh, Wql, x2h, x2l, Wkh, Wkl,
                                   q_bf, k_bf);
  // 3) v-proj
  v_proj<<<384, 256, 0, stream>>>(Wvh, x2h, vt_bf);
  // 4) attention (K dbuf 1-barrier pipeline, V reg-hoist, KSPLIT=2, swizzle)
  attn_mfma<<<768, 256, 0, stream>>>(q_bf, k_bf, vt_bf, aoacc, lacc, invt);
  // 5) Wo projection with fused slab-sum + ao-normalize staging
  wo_proj<<<96, 256, 0, stream>>>(aoacc, lacc, Woh, woout);
  // 6) final row l2norm
  l2norm_rows768_out<<<B1, 256, 0, stream>>>(woout, outp);
}

// Round 9
// 294.633 us; speedup vs baseline: 1.2206x; 1.0798x over previous
//
#include <hip/hip_runtime.h>
#include <hip/hip_bf16.h>
#include <math.h>

#define B1 2048
#define B2 8192
#define NH 12
#define DH 64
#define DMODEL 768

typedef __attribute__((ext_vector_type(8))) short short8;
typedef __attribute__((ext_vector_type(4))) float floatx4;
typedef __attribute__((ext_vector_type(8))) unsigned short ushort8;
typedef __attribute__((ext_vector_type(4))) unsigned short ushort4v;

static __device__ __forceinline__ unsigned short f2bf(float f) {
  __bf16 b = (__bf16)f;
  return __builtin_bit_cast(unsigned short, b);
}
static __device__ __forceinline__ float bf2f(unsigned short u) {
  return __builtin_bit_cast(float, ((unsigned)u) << 16);
}

// async global->LDS, 16B per lane; LDS dest = wave-uniform base + lane*16
static __device__ __forceinline__ void gload16(const unsigned short* g,
                                               unsigned short* l) {
  __builtin_amdgcn_global_load_lds(
      (const __attribute__((address_space(1))) void*)g,
      (__attribute__((address_space(3))) void*)l, 16, 0, 0);
}

// ---------------------------------------------------------------------------
// Fused prep: fp32 -> bf16. x1/x2: hi only (x-residual dropped; see qkv_proj
// precision note). Wq/Wk: hi+lo split. Wv/Wo: hi only.
// block-role table: [0,1536) x1 | [1536,7680) x2 | [7680,8256) Wq |
// [8256,8832) Wk | [8832,9408) Wv | [9408,9984) Wo
// ---------------------------------------------------------------------------
__global__ __launch_bounds__(256) void prep_all(
    const float* __restrict__ x1, unsigned short* __restrict__ x1h,
    const float* __restrict__ x2, unsigned short* __restrict__ x2h,
    const float* __restrict__ Wq, unsigned short* __restrict__ Wqh,
    unsigned short* __restrict__ Wql, const float* __restrict__ Wk,
    unsigned short* __restrict__ Wkh, unsigned short* __restrict__ Wkl,
    const float* __restrict__ Wv, unsigned short* __restrict__ Wvh,
    const float* __restrict__ Wo, unsigned short* __restrict__ Woh) {
  const int bi = blockIdx.x;
  const float* src;
  unsigned short *hi, *lo = nullptr;
  int lb;
  if (bi < 1536) {
    src = x1; hi = x1h; lb = bi;
  } else if (bi < 7680) {
    src = x2; hi = x2h; lb = bi - 1536;
  } else if (bi < 8256) {
    src = Wq; hi = Wqh; lo = Wql; lb = bi - 7680;
  } else if (bi < 8832) {
    src = Wk; hi = Wkh; lo = Wkl; lb = bi - 8256;
  } else if (bi < 9408) {
    src = Wv; hi = Wvh; lb = bi - 8832;
  } else {
    src = Wo; hi = Woh; lb = bi - 9408;
  }
  const int i = (lb * 256 + threadIdx.x) * 4;
  const float4 v = *(const float4*)&src[i];
  ushort4v h = {f2bf(v.x), f2bf(v.y), f2bf(v.z), f2bf(v.w)};
  *(ushort4v*)&hi[i] = h;
  if (lo) {
    ushort4v l = {f2bf(v.x - bf2f(h[0])), f2bf(v.y - bf2f(h[1])),
                  f2bf(v.z - bf2f(h[2])), f2bf(v.w - bf2f(h[3]))};
    *(ushort4v*)&lo[i] = l;
  }
}

// ---------------------------------------------------------------------------
// Core bf16 MFMA GEMM tile: C[M,N] = A[M,K]*B[N,K]^T (both K-contiguous).
// 128x128 tile, BK=32, 4 waves (2x2), 64x64/wave, global_load_lds staging,
// XOR-swizzled granules.
// BSPLIT: B held as hi+lo, 2-MFMA k-step => C = A_bf16 * B_full.
//   (A-residual term dropped: A is bf16-rounded downstream anyway, so the
//    extra 2^-9 relative error only raises operand error by ~sqrt(2).)
// L2N: per-64-col L2 norm epilogue.
// ---------------------------------------------------------------------------
template <bool BSPLIT, bool L2N, bool F32OUT>
static __device__ __forceinline__ void gemm_tile(
    const unsigned short* __restrict__ Ahg,
    const unsigned short* __restrict__ Bhg,
    const unsigned short* __restrict__ Blg,
    void* __restrict__ Cv, int M, int N, int K, int m0, int n0,
    unsigned short* sAh, unsigned short* sBh, unsigned short* sBl) {
  const int tid = threadIdx.x;
  const int wave = tid >> 6;
  const int lane = tid & 63;
  const int wm = wave >> 1;
  const int wn = wave & 1;
  const int n15 = lane & 15;
  const int quad = lane >> 4;
  const int srow = lane >> 2;
  const int cpl = (lane & 3) ^ (srow >> 2);

  floatx4 acc[4][4];
#pragma unroll
  for (int i = 0; i < 4; ++i)
#pragma unroll
    for (int j = 0; j < 4; ++j) acc[i][j] = (floatx4){0.f, 0.f, 0.f, 0.f};

  for (int k0 = 0; k0 < K; k0 += 32) {
    __syncthreads();
#pragma unroll
    for (int jj = 0; jj < 2; ++jj) {
      const int j = wave * 2 + jj;
      const int row = j * 16 + srow;
      const size_t goffA = (size_t)(m0 + row) * K + k0 + cpl * 8;
      const size_t goffB = (size_t)(n0 + row) * K + k0 + cpl * 8;
      gload16(Ahg + goffA, &sAh[j * 512]);
      gload16(Bhg + goffB, &sBh[j * 512]);
      if constexpr (BSPLIT) {
        gload16(Blg + goffB, &sBl[j * 512]);
      }
    }
    __syncthreads();

    short8 afh[4];
#pragma unroll
    for (int mt = 0; mt < 4; ++mt) {
      const int row = wm * 64 + mt * 16 + n15;
      const int off = row * 32 + ((quad ^ (n15 >> 2)) << 3);
      afh[mt] = *(const short8*)&sAh[off];
    }
#pragma unroll
    for (int nt = 0; nt < 4; ++nt) {
      const int row = wn * 64 + nt * 16 + n15;
      const int off = row * 32 + ((quad ^ (n15 >> 2)) << 3);
      const short8 bfh = *(const short8*)&sBh[off];
      if constexpr (BSPLIT) {
        const short8 bfl = *(const short8*)&sBl[off];
#pragma unroll
        for (int mt = 0; mt < 4; ++mt) {
          acc[mt][nt] = __builtin_amdgcn_mfma_f32_16x16x32_bf16(afh[mt], bfh, acc[mt][nt], 0, 0, 0);
          acc[mt][nt] = __builtin_amdgcn_mfma_f32_16x16x32_bf16(afh[mt], bfl, acc[mt][nt], 0, 0, 0);
        }
      } else {
#pragma unroll
        for (int mt = 0; mt < 4; ++mt)
          acc[mt][nt] = __builtin_amdgcn_mfma_f32_16x16x32_bf16(afh[mt], bfh, acc[mt][nt], 0, 0, 0);
      }
    }
  }

#pragma unroll
  for (int mt = 0; mt < 4; ++mt) {
    float scalev[4] = {1.f, 1.f, 1.f, 1.f};
    if constexpr (L2N) {
#pragma unroll
      for (int rr = 0; rr < 4; ++rr) {
        float ss = 0.f;
#pragma unroll
        for (int nt = 0; nt < 4; ++nt) ss += acc[mt][nt][rr] * acc[mt][nt][rr];
        ss += __shfl_xor(ss, 1, 64);
        ss += __shfl_xor(ss, 2, 64);
        ss += __shfl_xor(ss, 4, 64);
        ss += __shfl_xor(ss, 8, 64);
        scalev[rr] = 1.0f / fmaxf(sqrtf(ss), 1e-12f);
      }
    }
#pragma unroll
    for (int nt = 0; nt < 4; ++nt) {
#pragma unroll
      for (int rr = 0; rr < 4; ++rr) {
        const int row = m0 + wm * 64 + mt * 16 + quad * 4 + rr;
        const int col = n0 + wn * 64 + nt * 16 + n15;
        const float v = acc[mt][nt][rr] * scalev[rr];
        if constexpr (F32OUT)
          ((float*)Cv)[(size_t)row * N + col] = v;
        else
          ((unsigned short*)Cv)[(size_t)row * N + col] = f2bf(v);
      }
    }
  }
}

// ---------------------------------------------------------------------------
// Fused q-proj + k-proj + v-proj, one launch (864 blocks):
// [0,96) q (BSPLIT+L2N) | [96,480) k (BSPLIT+L2N) | [480,864) v (plain).
// ---------------------------------------------------------------------------
__global__ __launch_bounds__(256) void qkv_proj(
    const unsigned short* __restrict__ x1h,
    const unsigned short* __restrict__ Wqh, const unsigned short* __restrict__ Wql,
    const unsigned short* __restrict__ x2h,
    const unsigned short* __restrict__ Wkh, const unsigned short* __restrict__ Wkl,
    const unsigned short* __restrict__ Wvh,
    unsigned short* __restrict__ qbf, unsigned short* __restrict__ kbf,
    unsigned short* __restrict__ vtbf) {
  __shared__ __align__(16) unsigned short sAh[4096], sBh[4096], sBl[4096];
  const int bi = blockIdx.x;
  if (bi < 96) {
    gemm_tile<true, true, false>(x1h, Wqh, Wql, qbf, B1, DMODEL, DMODEL,
                                 (bi / 6) * 128, (bi % 6) * 128, sAh, sBh, sBl);
  } else if (bi < 480) {
    const int b = bi - 96;
    gemm_tile<true, true, false>(x2h, Wkh, Wkl, kbf, B2, DMODEL, DMODEL,
                                 (b / 6) * 128, (b % 6) * 128, sAh, sBh, sBl);
  } else {
    const int b = bi - 480;
    gemm_tile<false, false, false>(Wvh, x2h, nullptr, vtbf, DMODEL, B2, DMODEL,
                                   (b / 64) * 128, (b % 64) * 128, sAh, sBh, sBl);
  }
}

// ---------------------------------------------------------------------------
// MFMA bf16 attention — R8-verified structure (unchanged):
//  - K LDS double-buffered, ONE barrier per chunk; K prefetch 2 chunks deep.
//  - V loads hoisted to chunk start into regs, consumed by same-chunk PV.
//  - Ps wave-private LDS round trip; slab plain stores; XCD swizzle;
//    KSPLIT=2.
// ---------------------------------------------------------------------------
#define KC 128
#define KSPLIT 2
#define NCH (B2 / KSPLIT / KC)  // 32
#define PSTR 68

__global__ __launch_bounds__(256, 3) void attn_mfma(
    const unsigned short* __restrict__ qb, const unsigned short* __restrict__ kb,
    const unsigned short* __restrict__ vt, float* __restrict__ aoacc,
    float* __restrict__ lacc, const int* __restrict__ invt_p) {
  __shared__ __align__(16) unsigned short smem[25088];  // 50176 B
  // Kl dbuf: [2][128 keys][64 dims] at smem+0 / smem+8192 (shorts)
  unsigned short* Psl = smem + 16384;   // 4 waves x 32 x PSTR

  const int bid = blockIdx.x;                     // 0..767
  const int swz = (bid & 7) * 96 + (bid >> 3);    // bijective (768 % 8 == 0)
  const int zz = swz / 384;
  const int rem = swz - zz * 384;
  const int h = rem >> 5;
  const int q0 = (rem & 31) * 64;

  const float c2 = (float)invt_p[0] * 1.4426950408889634f;
  const int tid = threadIdx.x;
  const int wave = tid >> 6;
  const int lane = tid & 63;
  const int qsub = wave >> 1;
  const int ksub = wave & 1;
  const int n15 = lane & 15;
  const int quad = lane >> 4;
  const int kz0 = zz * (B2 / KSPLIT);

  unsigned short* Ps = &Psl[wave * 32 * PSTR];

  short8 qf[2][2];
#pragma unroll
  for (int qt = 0; qt < 2; ++qt)
#pragma unroll
    for (int ks = 0; ks < 2; ++ks) {
      const int qrow = q0 + qsub * 32 + qt * 16 + n15;
      qf[qt][ks] = *(const short8*)&qb[(size_t)qrow * DMODEL + h * DH + ks * 32 + quad * 8];
    }

  floatx4 oacc[2][4];
#pragma unroll
  for (int qt = 0; qt < 2; ++qt)
#pragma unroll
    for (int nt = 0; nt < 4; ++nt) oacc[qt][nt] = (floatx4){0.f, 0.f, 0.f, 0.f};
  float lsum[2] = {0.f, 0.f};

  const unsigned short* kbp = kb + (size_t)kz0 * DMODEL + h * DH;
  const unsigned short* vbp = vt + (size_t)(h * DH) * B2 + kz0;

  // prologue: load K chunk0 -> stage buf0 -> load K chunk1 -> barrier
  ushort8 kr[4];
#pragma unroll
  for (int i = 0; i < 4; ++i) {
    const int s = i * 256 + tid;
    const int key = s >> 3, cpk = s & 7, chk = cpk ^ (key & 7);
    kr[i] = *(const ushort8*)&kbp[(size_t)key * DMODEL + chk * 8];
  }
#pragma unroll
  for (int i = 0; i < 4; ++i) {
    const int s = i * 256 + tid;
    const int key = s >> 3, cpk = s & 7;
    *(ushort8*)&smem[key * 64 + cpk * 8] = kr[i];
  }
#pragma unroll
  for (int i = 0; i < 4; ++i) {
    const int s = i * 256 + tid;
    const int key = s >> 3, cpk = s & 7, chk = cpk ^ (key & 7);
    kr[i] = *(const ushort8*)&kbp[(size_t)(KC + key) * DMODEL + chk * 8];
  }
  __syncthreads();

  for (int c = 0; c < NCH; ++c) {
    unsigned short* Kb = &smem[(c & 1) * 8192];
    unsigned short* Kn = &smem[((c + 1) & 1) * 8192];
    const unsigned short* vc_ = vbp + c * KC;

    // early V issue for THIS chunk (consumed in PV below)
    ushort8 vr[8];
#pragma unroll
    for (int ks = 0; ks < 2; ++ks)
#pragma unroll
      for (int nt = 0; nt < 4; ++nt)
        vr[ks * 4 + nt] = *(const ushort8*)&vc_[
            (size_t)(nt * 16 + n15) * B2 + (ksub * 8 + ks * 4 + quad) * 8];

    // stage chunk c+1 into the other buffer; load chunk c+2
    if (c + 1 < NCH) {
#pragma unroll
      for (int i = 0; i < 4; ++i) {
        const int s = i * 256 + tid;
        const int key = s >> 3, cpk = s & 7;
        *(ushort8*)&Kn[key * 64 + cpk * 8] = kr[i];
      }
      if (c + 2 < NCH) {
        const unsigned short* k2 = kbp + (size_t)(c + 2) * KC * DMODEL;
#pragma unroll
        for (int i = 0; i < 4; ++i) {
          const int s = i * 256 + tid;
          const int key = s >> 3, cpk = s & 7, chk = cpk ^ (key & 7);
          kr[i] = *(const ushort8*)&k2[(size_t)key * DMODEL + chk * 8];
        }
      }
    }

    // ---- QK^T from Kb ----
#pragma unroll
    for (int kt = 0; kt < 4; ++kt) {
      floatx4 s0 = {0.f, 0.f, 0.f, 0.f}, s1 = {0.f, 0.f, 0.f, 0.f};
#pragma unroll
      for (int ks = 0; ks < 2; ++ks) {
        const int key = ksub * 64 + kt * 16 + n15;
        const int cp = (ks * 4 + quad) ^ (n15 & 7);
        const short8 kf = *(const short8*)&Kb[key * 64 + cp * 8];
        s0 = __builtin_amdgcn_mfma_f32_16x16x32_bf16(kf, qf[0][ks], s0, 0, 0, 0);
        s1 = __builtin_amdgcn_mfma_f32_16x16x32_bf16(kf, qf[1][ks], s1, 0, 0, 0);
      }
      ushort4v p0, p1;
#pragma unroll
      for (int r = 0; r < 4; ++r) {
        const float e0 = exp2f(fmaf(s0[r], c2, -c2));
        const float e1 = exp2f(fmaf(s1[r], c2, -c2));
        lsum[0] += e0;
        lsum[1] += e1;
        p0[r] = f2bf(e0);
        p1[r] = f2bf(e1);
      }
      *(ushort4v*)&Ps[(0 * 16 + n15) * PSTR + kt * 16 + quad * 4] = p0;
      *(ushort4v*)&Ps[(1 * 16 + n15) * PSTR + kt * 16 + quad * 4] = p1;
    }

    // ---- PV using prefetched vr ----
#pragma unroll
    for (int ks = 0; ks < 2; ++ks) {
      short8 pa[2];
#pragma unroll
      for (int qt = 0; qt < 2; ++qt)
        pa[qt] = *(const short8*)&Ps[(qt * 16 + n15) * PSTR + ks * 32 + quad * 8];
#pragma unroll
      for (int nt = 0; nt < 4; ++nt) {
        const short8 vf = __builtin_bit_cast(short8, vr[ks * 4 + nt]);
        oacc[0][nt] = __builtin_amdgcn_mfma_f32_16x16x32_bf16(pa[0], vf, oacc[0][nt], 0, 0, 0);
        oacc[1][nt] = __builtin_amdgcn_mfma_f32_16x16x32_bf16(pa[1], vf, oacc[1][nt], 0, 0, 0);
      }
    }

    __syncthreads();  // publish Kn; prior Kb readers done before next overwrite
  }

#pragma unroll
  for (int qt = 0; qt < 2; ++qt) {
    float v = lsum[qt];
    v += __shfl_xor(v, 16, 64);
    v += __shfl_xor(v, 32, 64);
    lsum[qt] = v;
  }

  float* aoz = aoacc + (size_t)zz * B1 * DMODEL;
  float* lz = lacc + (size_t)zz * B1 * NH;

  __syncthreads();
  float* Osc = (float*)smem;        // [64 q][64 d] f32 = 16384 B
  float* lsc = Osc + 4096;          // [64 q] f32 (total 16640 <= 50176)
  if (ksub == 1) {
#pragma unroll
    for (int qt = 0; qt < 2; ++qt)
#pragma unroll
      for (int nt = 0; nt < 4; ++nt)
#pragma unroll
        for (int r = 0; r < 4; ++r) {
          const int row = qsub * 32 + qt * 16 + quad * 4 + r;
          Osc[row * 64 + nt * 16 + n15] = oacc[qt][nt][r];
        }
    if (quad == 0) {
      lsc[qsub * 32 + n15] = lsum[0];
      lsc[qsub * 32 + 16 + n15] = lsum[1];
    }
  }
  __syncthreads();
  if (ksub == 0) {
#pragma unroll
    for (int qt = 0; qt < 2; ++qt)
#pragma unroll
      for (int nt = 0; nt < 4; ++nt)
#pragma unroll
        for (int r = 0; r < 4; ++r) {
          const int row = qsub * 32 + qt * 16 + quad * 4 + r;
          const float v = oacc[qt][nt][r] + Osc[row * 64 + nt * 16 + n15];
          aoz[(size_t)(q0 + row) * DMODEL + h * DH + nt * 16 + n15] = v;
        }
    if (quad == 0) {
      lz[(size_t)(q0 + qsub * 32 + n15) * NH + h] = lsum[0] + lsc[qsub * 32 + n15];
      lz[(size_t)(q0 + qsub * 32 + 16 + n15) * NH + h] =
          lsum[1] + lsc[qsub * 32 + 16 + n15];
    }
  }
}

// ---------------------------------------------------------------------------
// Wo projection with FUSED slab-sum + ao-normalize in A-staging:
// A[row][col] = bf16( (ao0+ao1)[row][col] / (l0+l1)[row][col>>6] ).
// B = Woh (gload16). C = f32 woout [B1, 768]. 96 blocks.
// ---------------------------------------------------------------------------
__global__ __launch_bounds__(256) void wo_proj(
    const float* __restrict__ aoacc, const float* __restrict__ lacc,
    const unsigned short* __restrict__ Woh, float* __restrict__ woout) {
  __shared__ __align__(16) unsigned short sAh[4096], sBh[4096];
  const int bi = blockIdx.x;
  const int m0 = (bi / 6) * 128;
  const int n0 = (bi % 6) * 128;
  const int tid = threadIdx.x;
  const int wave = tid >> 6;
  const int lane = tid & 63;
  const int wm = wave >> 1;
  const int wn = wave & 1;
  const int n15 = lane & 15;
  const int quad = lane >> 4;
  const int srow = lane >> 2;
  const int cpl = (lane & 3) ^ (srow >> 2);

  const float* ao1 = aoacc + (size_t)B1 * DMODEL;
  const float* la1 = lacc + (size_t)B1 * NH;

  floatx4 acc[4][4];
#pragma unroll
  for (int i = 0; i < 4; ++i)
#pragma unroll
    for (int j = 0; j < 4; ++j) acc[i][j] = (floatx4){0.f, 0.f, 0.f, 0.f};

  for (int k0 = 0; k0 < DMODEL; k0 += 32) {
    __syncthreads();
#pragma unroll
    for (int jj = 0; jj < 2; ++jj) {
      const int j = wave * 2 + jj;
      const int row = j * 16 + srow;
      // A: load 8 f32 from each slab, sum, normalize, convert, ds_write 16B
      const size_t ga = (size_t)(m0 + row) * DMODEL + k0 + cpl * 8;
      const float4 a0 = *(const float4*)&aoacc[ga];
      const float4 a1 = *(const float4*)&aoacc[ga + 4];
      const float4 b0 = *(const float4*)&ao1[ga];
      const float4 b1 = *(const float4*)&ao1[ga + 4];
      const int head = (k0 + cpl * 8) >> 6;
      const float lsum = lacc[(m0 + row) * NH + head] + la1[(m0 + row) * NH + head];
      const float inv = 1.0f / lsum;
      ushort8 ah = {f2bf((a0.x + b0.x) * inv), f2bf((a0.y + b0.y) * inv),
                    f2bf((a0.z + b0.z) * inv), f2bf((a0.w + b0.w) * inv),
                    f2bf((a1.x + b1.x) * inv), f2bf((a1.y + b1.y) * inv),
                    f2bf((a1.z + b1.z) * inv), f2bf((a1.w + b1.w) * inv)};
      *(ushort8*)&sAh[j * 512 + lane * 8] = ah;
      // B: async staging
      gload16(Woh + (size_t)(n0 + row) * DMODEL + k0 + cpl * 8, &sBh[j * 512]);
    }
    __syncthreads();

    short8 afh[4];
#pragma unroll
    for (int mt = 0; mt < 4; ++mt) {
      const int row = wm * 64 + mt * 16 + n15;
      afh[mt] = *(const short8*)&sAh[row * 32 + ((quad ^ (n15 >> 2)) << 3)];
    }
#pragma unroll
    for (int nt = 0; nt < 4; ++nt) {
      const int row = wn * 64 + nt * 16 + n15;
      const short8 bfh = *(const short8*)&sBh[row * 32 + ((quad ^ (n15 >> 2)) << 3)];
#pragma unroll
      for (int mt = 0; mt < 4; ++mt)
        acc[mt][nt] = __builtin_amdgcn_mfma_f32_16x16x32_bf16(afh[mt], bfh, acc[mt][nt], 0, 0, 0);
    }
  }

#pragma unroll
  for (int mt = 0; mt < 4; ++mt)
#pragma unroll
    for (int nt = 0; nt < 4; ++nt)
#pragma unroll
      for (int rr = 0; rr < 4; ++rr) {
        const int row = m0 + wm * 64 + mt * 16 + quad * 4 + rr;
        const int col = n0 + wn * 64 + nt * 16 + n15;
        woout[(size_t)row * DMODEL + col] = acc[mt][nt][rr];
      }
}

// ---------------------------------------------------------------------------
__global__ __launch_bounds__(256) void l2norm_rows768_out(
    const float* __restrict__ x, float* __restrict__ out) {
  const int row = blockIdx.x;
  const float* xr = &x[(size_t)row * DMODEL];
  float ss = 0.0f;
  float vals[3];
#pragma unroll
  for (int i = 0; i < 3; ++i) {
    vals[i] = xr[threadIdx.x + i * 256];
    ss += vals[i] * vals[i];
  }
#pragma unroll
  for (int off = 32; off > 0; off >>= 1) ss += __shfl_xor(ss, off, 64);
  __shared__ float ws[4];
  if ((threadIdx.x & 63) == 0) ws[threadIdx.x >> 6] = ss;
  __syncthreads();
  const float tot = ws[0] + ws[1] + ws[2] + ws[3];
  const float sc = 1.0f / fmaxf(sqrtf(tot), 1e-12f);
  float* orow = &out[(size_t)row * DMODEL];
#pragma unroll
  for (int i = 0; i < 3; ++i) orow[threadIdx.x + i * 256] = vals[i] * sc;
}

// ---------------------------------------------------------------------------
extern "C" void kernel_launch(void* const* d_in, const int* in_sizes, int n_in,
                              void* d_out, int out_size, void* d_ws,
                              size_t ws_size, hipStream_t stream) {
  const float* x1 = (const float*)d_in[0];
  const float* x2 = (const float*)d_in[1];
  const float* Wq = (const float*)d_in[2];
  const float* Wk = (const float*)d_in[3];
  const float* Wv = (const float*)d_in[4];
  const float* Wo = (const float*)d_in[5];
  const int* invt = (const int*)d_in[6];
  float* outp = (float*)d_out;

  // workspace (bytes). Aliases are lifetime-safe under stream serialization:
  //  aoacc slab0 <- x1h region + pad (x1h dead after qkv)   [0,        6291456)
  //  aoacc slab1 <- x2h first half (dead after qkv)         [6291456, 12582912)
  //  woout       <- x2h second half (dead after qkv)        [12582912,18874368)
  //  vt_bf       <- old x2l region (unused now)             [18874368,31457280)
  //  lacc slabs  <- Wql-adjacent scratch (dead after qkv)   [32636928,32833536)
  char* ws = (char*)d_ws;
  unsigned short* x1h = (unsigned short*)(ws + 0);
  unsigned short* x2h = (unsigned short*)(ws + 6291456);
  unsigned short* Wqh = (unsigned short*)(ws + 31457280);
  unsigned short* Wql = (unsigned short*)(ws + 32636928);
  unsigned short* Wkh = (unsigned short*)(ws + 33816576);
  unsigned short* Wkl = (unsigned short*)(ws + 34996224);
  unsigned short* Wvh = (unsigned short*)(ws + 36175872);
  unsigned short* Woh = (unsigned short*)(ws + 37355520);
  unsigned short* q_bf = (unsigned short*)(ws + 38535168);
  unsigned short* k_bf = (unsigned short*)(ws + 41680896);   // end 54263808
  // aliases:
  float* aoacc = (float*)(ws + 0);                  // 2 slabs, 12582912 B
  float* lacc = (float*)(ws + 32636928);            // 2 slabs over Wql region
  unsigned short* vt_bf = (unsigned short*)(ws + 18874368);
  float* woout = (float*)(ws + 12582912);

  // 1) prep (x1/x2 hi-only; Wq/Wk hi+lo; Wv/Wo hi)
  prep_all<<<9984, 256, 0, stream>>>(x1, x1h, x2, x2h, Wq, Wqh, Wql,
                                     Wk, Wkh, Wkl, Wv, Wvh, Wo, Woh);
  // 2) q+k+v projections fused, one launch (2-MFMA B-split for q/k)
  qkv_proj<<<864, 256, 0, stream>>>(x1h, Wqh, Wql, x2h, Wkh, Wkl, Wvh,
                                    q_bf, k_bf, vt_bf);
  // 3) attention (R8-verified pipeline)
  attn_mfma<<<768, 256, 0, stream>>>(q_bf, k_bf, vt_bf, aoacc, lacc, invt);
  // 4) Wo projection with fused slab-sum + ao-normalize staging
  wo_proj<<<96, 256, 0, stream>>>(aoacc, lacc, Woh, woout);
  // 5) final row l2norm
  l2norm_rows768_out<<<B1, 256, 0, stream>>>(woout, outp);
}